// Round 15
// baseline (294.447 us; speedup 1.0000x reference)
//
#include <hip/hip_runtime.h>
#include <cstdint>

// ===========================================================================
// KWS_LSTM_bmm — exact integer reformulation, fp32-faithful quant decisions.
// R15 = R14 + prep_w folded into lstm_k via cooperative LDS transpose
//   (removes the ~75 µs second-kernel + gap overhead; R11's failure mode
//   avoided: loads fully coalesced, staging stride 72 keeps write banks
//   4-way and b64 gathers ~2-way).
//   * prolog per chunk (x:40 rows, h:64x3+8 rows): coalesced dword loads ->
//     q8f -> ds_write_b32 into wstage[col*72+k] -> barrier -> each lane
//     gathers its 16-B fragment (2x ds_read_b64) -> barrier.
//   * junk safety: gather indices clamped; ew writes gok-guarded; h cols
//     200..255 are zero (absorb chunk-4 junk); x-chunk k>=40 masked to 0
//     in-register (q==2 hi half, q==3 all) exactly as prep_w did.
//   * wstage overlays the xq region (57.6 KB, filled after the last gather).
//   * everything else verbatim R14: grid 256 = 8n x 32 eight-row tiles,
//     13 waves, MFMA i8 16x16x64 (x chunk in barrier shadow, h = 4 chunks),
//     2 ew items/lane via C-row duplication, all xq prestaged, exact LUTs.
// Exactness: every lattice chain bit-exact in fp32 (numerators < 2^24).
// ===========================================================================

typedef int v4i __attribute__((ext_vector_type(4)));

#define SEQn 101
#define BLK  832              // 13 waves
#define HST  288              // h row stride (2-way banks on b128 reads)
#define HSLOT 2304            // 8 rows
#define SIG_OFF 22720
#define SIG_SZ  41152         // sigmoid q-LUT (idx >= 41152 saturates to 127)
#define TMAX 10527            // |tanh| saturation index
#define WSTRIDE 72            // staging bytes/col (4-way write banks, b64-aligned)

// LDS layout (tables low: gathers fold base into 16-bit ds offset-imm)
#define L_SIGT  0             // u8[41152]
#define L_TANH  41152         // i8[10528]  |tanh| magnitude table
#define L_TANC  51680         // float[255]
#define L_FCRED 52704         // int[128]
#define L_VOUT  53216         // float[16]
#define L_XQ    53280         // overlay: wstage i8[800*72]=57600 (prolog),
                              //          then xq i8[101][8*64]=51712
#define L_HBUF  110880        // i8[2][HSLOT] 4608 B
#define L_TOTAL 115488

__device__ __forceinline__ int q8f(float v) {        // rint(clip(v*128, ±127))
    float t = fminf(fmaxf(v * 128.0f, -127.0f), 127.0f);
    return (int)rintf(t);
}

// fp32-faithful qp(x, a1=128, 8) on raw inputs
__device__ __forceinline__ int xq_f32(float xv) {
    float ax  = fabsf(xv);
    float d   = ax - 128.0f;
    float u   = ax - fabsf(d);
    float v   = u + 128.0f;
    float p   = 0.5f * v;
    float x01 = p * 0.0078125f;
    x01 = fminf(x01, 0.9921875f);
    int q = (int)rintf(x01 * 128.0f);
    return (xv < 0.0f) ? -q : q;
}

// ---------------- single persistent kernel ----------------------------------
__global__ __launch_bounds__(BLK) void lstm_k(const float* __restrict__ x,
                                              const float* __restrict__ w_ih,
                                              const float* __restrict__ w_hh,
                                              const float* __restrict__ b_ih,
                                              const float* __restrict__ b_hh,
                                              const float* __restrict__ fw,
                                              const float* __restrict__ fb,
                                              float* __restrict__ out) {
    __shared__ __align__(16) unsigned char smem[L_TOTAL];
    unsigned char* sigt  = smem + L_SIGT;
    signed char*   tanh8 = (signed char*)(smem + L_TANH);
    float*         tanc  = (float*)(smem + L_TANC);
    int*           fcred = (int*)(smem + L_FCRED);
    float*         vout  = (float*)(smem + L_VOUT);
    signed char*   wstage= (signed char*)(smem + L_XQ);  // prolog overlay
    signed char*   xq    = (signed char*)(smem + L_XQ);
    signed char*   hbuf  = (signed char*)(smem + L_HBUF);

    const int tid  = threadIdx.x;
    const int n    = blockIdx.x >> 5;                // 0..7
    const int b0   = (blockIdx.x & 31) * 8;          // batch base (8 rows/WG)
    const int W    = tid >> 6;                       // wave 0..12, col-tile W
    const int lane = tid & 63;
    const int q    = lane >> 4;                      // quad
    const int c    = lane & 15;                      // A row (c&7 real) / B col
    const int arow = c & 7;                          // A rows 8-15 duplicate 0-7
    const int colW = 16 * W + c;
    const bool gok = (colW < 200);
    const bool hi  = (q & 2) != 0;                   // this lane uses acc regs 2,3

    // ---- zero h buffers (h0 = 0; cols 200..287 stay 0 forever) ----
    for (int i = tid; i < (2 * HSLOT) / 4; i += BLK) ((int*)hbuf)[i] = 0;

    // ---- exact quant LUTs: fast fp32 chain, fp64 fallback within 2e-3 of a
    //      rint half-boundary (proven R2-R14, verbatim) ----
    for (int i = tid; i < SIG_SZ; i += BLK) {
        float g = (float)(i - SIG_OFF) * (1.0f / 4096.0f);
        float s = 1.0f / (1.0f + expf(-g));
        float d = s - 1.0f;
        float u = s - fabsf(d);
        float p = 0.5f * (u + 1.0f);
        float t = fminf(fmaxf(p, -0.9921875f), 0.9921875f) * 128.0f;
        float rq = rintf(t);
        int qv = (int)rq;
        if (fabsf(t - rq) > 0.498f) {
            float s2 = 1.0f / (1.0f + (float)exp(-(double)g));
            float d2 = s2 - 1.0f;
            float u2 = s2 - fabsf(d2);
            float p2 = 0.5f * (u2 + 1.0f);
            qv = (int)rintf(fminf(fmaxf(p2, -0.9921875f), 0.9921875f) * 128.0f);
        }
        sigt[i] = (unsigned char)qv;
    }
    for (int i = tid; i < TMAX + 1; i += BLK) {      // |tanh| magnitude table
        float ag = (float)i * (1.0f / 4096.0f);
        float t0 = tanhf(ag);
        float d = t0 - 1.0f;
        float u = t0 - fabsf(d);
        float p = 0.5f * (u + 1.0f);
        float t = fminf(fmaxf(p, -0.9921875f), 0.9921875f) * 128.0f;
        float rq = rintf(t);
        int qv = (int)rq;
        if (fabsf(t - rq) > 0.498f) {
            float t2 = (float)tanh((double)ag);
            float d2 = t2 - 1.0f;
            float u2 = t2 - fabsf(d2);
            float p2 = 0.5f * (u2 + 1.0f);
            qv = (int)rintf(fminf(fmaxf(p2, -0.9921875f), 0.9921875f) * 128.0f);
        }
        tanh8[i] = (signed char)qv;
    }
    if (tid < 255) {                                 // float tanh(nc/32), idx = nc+127
        int nc = tid - 127;
        float t2 = (float)tanh((double)abs(nc) * (1.0 / 32.0));
        float d2 = t2 - 1.0f;
        float u2 = t2 - fabsf(d2);
        float p2 = 0.5f * (u2 + 1.0f);
        int qv = (int)rintf(fminf(fmaxf(p2, -0.9921875f), 0.9921875f) * 128.0f);
        tanc[tid] = (float)(nc < 0 ? -qv : qv);
    }

    // ---- bias per gate: sigmoid gates bake SIG_OFF; j-gate raw (sign path) --
    int bias[4];
    #pragma unroll
    for (int G = 0; G < 4; ++G) {
        int off = (G == 1) ? 0 : SIG_OFF;
        bias[G] = gok
            ? 32 * (q8f(b_ih[n * 800 + G * 200 + colW]) + q8f(b_hh[n * 800 + G * 200 + colW])) + off
            : off;
    }

    // ---- weight staging: 5 chunks, cooperative transpose through LDS ----
    // chunk 0: w_ih rows 0..39; chunks 1..3: w_hh 64 rows; chunk 4: rows 192..199.
    // wstage[col*72 + k] = q8f(w[row k][col]); gather = 2x ds_read_b64 per G.
    v4i Bv[4][5];
    const int gcol = (colW < 200) ? colW : 207;      // junk lanes read in-bounds garbage
    #pragma unroll
    for (int ch = 0; ch < 5; ++ch) {
        __syncthreads();                             // prev gather done / LUT phase done
        const int nrq = (ch == 0) ? 10 : (ch == 4 ? 2 : 16);
        const float* src = (ch == 0) ? (w_ih + (size_t)n * 40 * 800)
                                     : (w_hh + ((size_t)n * 200 + 64 * (ch - 1)) * 800);
        for (int u = tid; u < 800 * nrq; u += BLK) {
            int col = u % 800, rq = u / 800;
            const float* sp = src + (size_t)(4 * rq) * 800 + col;
            int p0 = q8f(sp[0]);
            int p1 = q8f(sp[800]);
            int p2 = q8f(sp[1600]);
            int p3 = q8f(sp[2400]);
            unsigned int pk = (p0 & 255) | ((p1 & 255) << 8) | ((p2 & 255) << 16)
                            | ((unsigned)(p3 & 255) << 24);
            *(unsigned int*)(wstage + col * WSTRIDE + 4 * rq) = pk;
        }
        __syncthreads();                             // chunk staged
        #pragma unroll
        for (int G = 0; G < 4; ++G) {
            const signed char* gp = wstage + (G * 200 + gcol) * WSTRIDE + 16 * q;
            union { unsigned long long u[2]; v4i v; } cv;
            cv.u[0] = *(const unsigned long long*)(gp);
            cv.u[1] = *(const unsigned long long*)(gp + 8);
            v4i bv = cv.v;
            if (ch == 0) {                           // x chunk: mask k_in >= 40
                if (q == 2) { bv[2] = 0; bv[3] = 0; }
                if (q == 3) bv = (v4i){0, 0, 0, 0};
            }
            Bv[G][ch] = bv;                          // chunk-4 junk k hits zero h-cols
        }
    }
    __syncthreads();                                 // all gathers done -> reuse region

    // ---- prestage ALL xq (fp32-faithful, coalesced); bytes 40..63/row junk
    //      but x-chunk B is masked there (above) ----
    for (int i = tid; i < SEQn * 320; i += BLK) {
        int t = i / 320; int rem = i - t * 320;      // rem = row*40 + k
        int row = rem / 40; int k = rem - row * 40;
        float xv = x[(size_t)t * 10240 + (size_t)b0 * 40 + rem];
        xq[t * 512 + row * 64 + k] = (signed char)xq_f32(xv);
    }

    // lane item identity: rows rowbase+rr (rr=0,1) from acc regs (q&2)+rr
    const int rowbase = 4 * (q & 1) + (q & 2);
    float cstf[2] = {0.f, 0.f};
    const signed char* xqv = xq + arow * 64 + 16 * q;
    const signed char* hbRb = hbuf + arow * HST + 16 * q;
    signed char* wrbb = hbuf + rowbase * HST + colW;
    const v4i zq = (v4i){0, 0, 0, 0};
    __syncthreads();                                 // xq ready

    // ---- shadow for t=0: x-chunk MFMA + x32 + bias ----
    v4i a0[4];
    {
        v4i ax = *(const v4i*)(xqv);
        #pragma unroll
        for (int G = 0; G < 4; ++G) {
            v4i tx = __builtin_amdgcn_mfma_i32_16x16x64_i8(ax, Bv[G][0], zq, 0, 0, 0);
            a0[G] = tx * 32 + bias[G];
        }
    }

    // ======================= time loop (1 barrier/step) =======================
    #pragma clang loop unroll(disable)
    for (int t = 0; t < SEQn; ++t) {
        __syncthreads();                             // h(t) ready

        // h-part: 4 chunks K=64, accumulate onto 32*x + bias
        const signed char* hbR = hbRb + (t & 1) * HSLOT;
        #pragma unroll
        for (int m = 1; m <= 4; ++m) {
            v4i ah = *(const v4i*)(hbR + 64 * (m - 1));
            #pragma unroll
            for (int G = 0; G < 4; ++G)
                a0[G] = __builtin_amdgcn_mfma_i32_16x16x64_i8(ah, Bv[G][m], a0[G], 0, 0, 0);
        }

        // ---- ew: 2 items/lane (rows rowbase+rr, acc regs (q&2)+rr) ----
        signed char* wrb = wrbb + ((t + 1) & 1) * HSLOT;
        int ix_i[2], ix_f[2], ix_o[2], gj_[2];
        #pragma unroll
        for (int rr = 0; rr < 2; ++rr) {
            int gi = hi ? a0[0][2 + rr] : a0[0][rr];
            int gj = hi ? a0[1][2 + rr] : a0[1][rr];
            int gf = hi ? a0[2][2 + rr] : a0[2][rr];
            int go = hi ? a0[3][2 + rr] : a0[3][rr];
            ix_i[rr] = min(max(gi, 0), SIG_SZ - 1);  // clamp = true saturation
            ix_f[rr] = min(max(gf, 0), SIG_SZ - 1);
            ix_o[rr] = min(max(go, 0), SIG_SZ - 1);
            gj_[rr]  = gj;
        }
        int qi[2], qf[2], qo[2], qj[2];
        #pragma unroll
        for (int rr = 0; rr < 2; ++rr) {             // level-1 gathers (offset-imm)
            qi[rr] = sigt[ix_i[rr]];
            qf[rr] = sigt[ix_f[rr]];
            qo[rr] = sigt[ix_o[rr]];
            qj[rr] = tanh8[min(abs(gj_[rr]), TMAX)];
        }
        float ncv[2]; int id2[2];
        #pragma unroll
        for (int rr = 0; rr < 2; ++rr) {
            int qjs = (gj_[rr] < 0) ? -qj[rr] : qj[rr];             // odd symmetry, bit-exact
            float gc = rintf(cstf[rr] * (float)qf[rr]);             // rint(cst*qf/128), exact
            float ai = rintf((float)qi[rr] * 0.0078125f * (float)qjs); // rint(qi*qj/128), exact
            float nc = rintf(fminf(fmaxf(fmaf(ai, 0.25f, gc), -127.0f), 127.0f));
            ncv[rr] = nc;
            id2[rr] = (int)(nc + 127.0f);
        }
        float ac[2];
        #pragma unroll
        for (int rr = 0; rr < 2; ++rr) ac[rr] = tanc[id2[rr]];      // level-2 gathers
        #pragma unroll
        for (int rr = 0; rr < 2; ++rr) {
            cstf[rr] = ncv[rr] * 0.0078125f;
            int nh = (int)rintf(ac[rr] * (float)qo[rr] * 0.001953125f); // rint(p/512), exact
            if (gok) wrb[rr * HST] = (signed char)nh;               // h(t+1)
        }

        // ---- shadow for t+1: x-chunk MFMA + x32 + bias ----
        if (t != SEQn - 1) {
            v4i ax = *(const v4i*)(xqv + (t + 1) * 512);
            #pragma unroll
            for (int G = 0; G < 4; ++G) {
                v4i tx = __builtin_amdgcn_mfma_i32_16x16x64_i8(ax, Bv[G][0], zq, 0, 0, 0);
                a0[G] = tx * 32 + bias[G];
            }
        }
    }
    __syncthreads();                                 // hT = h(101) in parity 1

    // ---- finFC: out_pre = (S + 32*qfb)/4096, then qp(.., fa2=16) ----
    const signed char* hT = hbuf + 1 * HSLOT;
    if (tid < 128) {
        int b = tid >> 4, oo = (tid >> 3) & 1, ch = tid & 7;
        int S = 0;
        for (int g2 = ch * 25; g2 < ch * 25 + 25; ++g2)
            S += (int)hT[b * HST + g2] * q8f(fw[(n * 200 + g2) * 2 + oo]);
        fcred[tid] = S;
    }
    __syncthreads();
    if (tid < 16) {
        int b = tid >> 1, oo = tid & 1;
        int S = 0;
        #pragma unroll
        for (int ch = 0; ch < 8; ++ch) S += fcred[b * 16 + oo * 8 + ch];
        S += 32 * q8f(fb[n * 2 + oo]);
        float f = fminf(fmaxf((float)S * 0.001953125f, -127.f), 127.f);
        int qo2 = (int)rintf(f);
        vout[tid] = (float)qo2 * 0.125f;
    }
    __syncthreads();
    if (tid < 16) {
        int b = tid >> 1, oo = tid & 1;
        int bg = b0 + b;
        if (n < 4) { if (oo == 0) out[bg * 12 + n] = vout[b * 2] + vout[b * 2 + 1]; }
        else out[bg * 12 + 4 + 2 * (n - 4) + oo] = vout[b * 2 + oo];
    }
}

// ---------------------------------------------------------------------------
extern "C" void kernel_launch(void* const* d_in, const int* in_sizes, int n_in,
                              void* d_out, int out_size, void* d_ws, size_t ws_size,
                              hipStream_t stream) {
    (void)in_sizes; (void)n_in; (void)out_size; (void)d_ws; (void)ws_size;
    const float* x    = (const float*)d_in[0];
    const float* w_ih = (const float*)d_in[1];
    const float* w_hh = (const float*)d_in[2];
    const float* b_ih = (const float*)d_in[3];
    const float* b_hh = (const float*)d_in[4];
    const float* fw   = (const float*)d_in[15];
    const float* fb   = (const float*)d_in[16];

    lstm_k<<<256, BLK, 0, stream>>>(x, w_ih, w_hh, b_ih, b_hh, fw, fb, (float*)d_out);
}

// Round 16
// 245.037 us; speedup vs baseline: 1.2016x; 1.2016x over previous
//
#include <hip/hip_runtime.h>
#include <cstdint>

// ===========================================================================
// KWS_LSTM_bmm — exact integer reformulation, fp32-faithful quant decisions.
// R16 = R14 (revert of R15's in-kernel weight fold — the ~68 µs "gap" is
// fixed harness overhead, and the in-kernel transpose cost +59 µs) + fused
// transposed nh table:
//   * T2[qo*256 + (nc+127)] = rint(tanc(nc)*qo/512) (i8, 32 KB). qo*256 is
//     0 mod 128 B -> LDS bank driven by nc (well-spread), fixing R11's
//     qo-clustered banking. Replaces the tanc float gather + mul/rint/cvt
//     tail with one byte gather (shorter post-gather serial tail).
//   * everything else verbatim R14: prep_w kernel + grid 256 = 8n x 32
//     eight-row tiles, 13 waves, MFMA i8 16x16x64 (x chunk in barrier
//     shadow, h = 4 chunks), 2 ew items/lane via C-row duplication, all xq
//     prestaged in LDS, exact LUTs (fast fp32 + 0.498-margin fp64 fallback).
// Exactness: every lattice chain bit-exact in fp32 (numerators < 2^24).
// ===========================================================================

typedef int v4i __attribute__((ext_vector_type(4)));

#define SEQn 101
#define BLK  832              // 13 waves
#define HST  288              // h row stride (2-way banks on b128 reads)
#define HSLOT 2304            // 8 rows
#define SIG_OFF 22720
#define SIG_SZ  41152         // sigmoid q-LUT (idx >= 41152 saturates to 127)
#define TMAX 10527            // |tanh| saturation index

// LDS layout (tables low: gathers fold base into 16-bit ds offset-imm)
#define L_SIGT  0             // u8[41152]
#define L_TANH  41152         // i8[10528]  |tanh| magnitude table
#define L_TANCV 51680         // float[256] (build staging for T2)
#define L_T2    52736         // i8[128*256] = 32768 (base = 412*128)
#define L_FCRED 85504         // int[128]
#define L_VOUT  86016         // float[16]
#define L_XQ    86080         // i8[101][8*64] = 51712
#define L_HBUF  137792        // i8[2][HSLOT] = 4608
#define L_TOTAL 142400

__device__ __forceinline__ int q8f(float v) {        // rint(clip(v*128, ±127))
    float t = fminf(fmaxf(v * 128.0f, -127.0f), 127.0f);
    return (int)rintf(t);
}

// fp32-faithful qp(x, a1=128, 8) on raw inputs
__device__ __forceinline__ int xq_f32(float xv) {
    float ax  = fabsf(xv);
    float d   = ax - 128.0f;
    float u   = ax - fabsf(d);
    float v   = u + 128.0f;
    float p   = 0.5f * v;
    float x01 = p * 0.0078125f;
    x01 = fminf(x01, 0.9921875f);
    int q = (int)rintf(x01 * 128.0f);
    return (xv < 0.0f) ? -q : q;
}

// ---------------- kernel 1: weight quant + K64 B-fragment packing ----------
// wsl[o], o = ((((n*13+t)*4+G)*5+ch)*64 + lane)*2 + h
// fragment byte p = 8h+jj of lane (q,c): k_in_chunk = 16q + 8h + jj
// ch0 = x chunk (k<40 from w_ih); ch1..4 = h chunks (kk = 64(ch-1)+k_in < 200)
__global__ __launch_bounds__(256) void prep_w(const float* __restrict__ w_ih,
                                              const float* __restrict__ w_hh,
                                              unsigned long long* __restrict__ wsl) {
    int o = blockIdx.x * 256 + threadIdx.x;          // 0..266239
    int h = o & 1; int l = (o >> 1) & 63; int r = o >> 7;
    int ch = r % 5; r /= 5;
    int G = r & 3;  r >>= 2;
    int t = r % 13; int n = r / 13;
    int q = l >> 4, cc = l & 15;
    int colW = 16 * t + cc;
    unsigned long long pack = 0ull;
    if (colW < 200) {
        int col = G * 200 + colW;
        #pragma unroll
        for (int jj = 0; jj < 8; ++jj) {
            int k_in = 16 * q + 8 * h + jj;
            int v = 0;
            if (ch == 0) { if (k_in < 40) v = q8f(w_ih[(n * 40 + k_in) * 800 + col]); }
            else { int kk = 64 * (ch - 1) + k_in; if (kk < 200) v = q8f(w_hh[(n * 200 + kk) * 800 + col]); }
            pack |= (unsigned long long)((unsigned)v & 0xffu) << (8 * jj);
        }
    }
    wsl[o] = pack;
}

// ---------------- kernel 2: persistent LSTM ---------------------------------
__global__ __launch_bounds__(BLK) void lstm_k(const float* __restrict__ x,
                                              const float* __restrict__ b_ih,
                                              const float* __restrict__ b_hh,
                                              const float* __restrict__ fw,
                                              const float* __restrict__ fb,
                                              const unsigned long long* __restrict__ wsl,
                                              float* __restrict__ out) {
    __shared__ __align__(16) unsigned char smem[L_TOTAL];
    unsigned char* sigt  = smem + L_SIGT;
    signed char*   tanh8 = (signed char*)(smem + L_TANH);
    float*         tancv = (float*)(smem + L_TANCV);
    signed char*   T2    = (signed char*)(smem + L_T2);
    int*           fcred = (int*)(smem + L_FCRED);
    float*         vout  = (float*)(smem + L_VOUT);
    signed char*   xq    = (signed char*)(smem + L_XQ);
    signed char*   hbuf  = (signed char*)(smem + L_HBUF);

    const int tid  = threadIdx.x;
    const int n    = blockIdx.x >> 5;                // 0..7
    const int b0   = (blockIdx.x & 31) * 8;          // batch base (8 rows/WG)
    const int W    = tid >> 6;                       // wave 0..12, col-tile W
    const int lane = tid & 63;
    const int q    = lane >> 4;                      // quad
    const int c    = lane & 15;                      // A row (c&7 real) / B col
    const int arow = c & 7;                          // A rows 8-15 duplicate 0-7
    const int colW = 16 * W + c;
    const bool gok = (colW < 200);
    const bool hi  = (q & 2) != 0;                   // this lane uses acc regs 2,3

    // ---- zero h buffers (h0 = 0; junk cols stay 0) ----
    for (int i = tid; i < (2 * HSLOT) / 4; i += BLK) ((int*)hbuf)[i] = 0;

    // ---- exact quant LUTs: fast fp32 chain, fp64 fallback within 2e-3 of a
    //      rint half-boundary (proven R2-R15, verbatim) ----
    for (int i = tid; i < SIG_SZ; i += BLK) {
        float g = (float)(i - SIG_OFF) * (1.0f / 4096.0f);
        float s = 1.0f / (1.0f + expf(-g));
        float d = s - 1.0f;
        float u = s - fabsf(d);
        float p = 0.5f * (u + 1.0f);
        float t = fminf(fmaxf(p, -0.9921875f), 0.9921875f) * 128.0f;
        float rq = rintf(t);
        int qv = (int)rq;
        if (fabsf(t - rq) > 0.498f) {
            float s2 = 1.0f / (1.0f + (float)exp(-(double)g));
            float d2 = s2 - 1.0f;
            float u2 = s2 - fabsf(d2);
            float p2 = 0.5f * (u2 + 1.0f);
            qv = (int)rintf(fminf(fmaxf(p2, -0.9921875f), 0.9921875f) * 128.0f);
        }
        sigt[i] = (unsigned char)qv;
    }
    for (int i = tid; i < TMAX + 1; i += BLK) {      // |tanh| magnitude table
        float ag = (float)i * (1.0f / 4096.0f);
        float t0 = tanhf(ag);
        float d = t0 - 1.0f;
        float u = t0 - fabsf(d);
        float p = 0.5f * (u + 1.0f);
        float t = fminf(fmaxf(p, -0.9921875f), 0.9921875f) * 128.0f;
        float rq = rintf(t);
        int qv = (int)rq;
        if (fabsf(t - rq) > 0.498f) {
            float t2 = (float)tanh((double)ag);
            float d2 = t2 - 1.0f;
            float u2 = t2 - fabsf(d2);
            float p2 = 0.5f * (u2 + 1.0f);
            qv = (int)rintf(fminf(fmaxf(p2, -0.9921875f), 0.9921875f) * 128.0f);
        }
        tanh8[i] = (signed char)qv;
    }
    if (tid < 256) {                                 // tanc values (fp64-faithful)
        int nc = min(tid, 254) - 127;
        float t2 = (float)tanh((double)abs(nc) * (1.0 / 32.0));
        float d2 = t2 - 1.0f;
        float u2 = t2 - fabsf(d2);
        float p2 = 0.5f * (u2 + 1.0f);
        int qv = (int)rintf(fminf(fmaxf(p2, -0.9921875f), 0.9921875f) * 128.0f);
        tancv[tid] = (float)(nc < 0 ? -qv : qv);
    }

    // ---- register-resident K64 B fragments (coalesced 16B/lane loads) ----
    v4i Bv[4][5];
    {
        const unsigned long long* bb = wsl + (size_t)(n * 13 + W) * 4 * 5 * 128;
        #pragma unroll
        for (int G = 0; G < 4; ++G)
            #pragma unroll
            for (int ch = 0; ch < 5; ++ch) {
                unsigned long long lo = bb[(size_t)(G * 5 + ch) * 128 + lane * 2];
                unsigned long long hi2 = bb[(size_t)(G * 5 + ch) * 128 + lane * 2 + 1];
                union { unsigned long long u[2]; v4i v; } cv;
                cv.u[0] = lo; cv.u[1] = hi2;
                Bv[G][ch] = cv.v;
            }
    }

    // ---- bias per gate: sigmoid gates bake SIG_OFF; j-gate raw (sign path) --
    int bias[4];
    #pragma unroll
    for (int G = 0; G < 4; ++G) {
        int off = (G == 1) ? 0 : SIG_OFF;
        bias[G] = gok
            ? 32 * (q8f(b_ih[n * 800 + G * 200 + colW]) + q8f(b_hh[n * 800 + G * 200 + colW])) + off
            : off;
    }
    __syncthreads();                                 // tancv ready; zero phases done

    // ---- fused nh table: T2[qo*256 + nc+127] = rint(tanc*qo/512), exact ----
    for (int i = tid; i < 128 * 256; i += BLK) {
        int qo2 = i >> 8, nci = i & 255;
        float tv = tancv[nci < 255 ? nci : 254];
        T2[i] = (signed char)(int)rintf(tv * (float)qo2 * 0.001953125f);
    }

    // ---- prestage ALL xq (fp32-faithful, coalesced) ----
    for (int i = tid; i < SEQn * 320; i += BLK) {
        int t = i / 320; int rem = i - t * 320;      // rem = row*40 + k
        int row = rem / 40; int k = rem - row * 40;
        float xv = x[(size_t)t * 10240 + (size_t)b0 * 40 + rem];
        xq[t * 512 + row * 64 + k] = (signed char)xq_f32(xv);
    }

    // lane item identity: rows rowbase+rr (rr=0,1) from acc regs (q&2)+rr
    const int rowbase = 4 * (q & 1) + (q & 2);
    float cstf[2] = {0.f, 0.f};
    const signed char* xqv = xq + arow * 64 + 16 * q;
    const signed char* hbRb = hbuf + arow * HST + 16 * q;
    signed char* wrbb = hbuf + rowbase * HST + colW;
    const v4i zq = (v4i){0, 0, 0, 0};
    __syncthreads();                                 // T2 + xq ready

    // ---- shadow for t=0: x-chunk MFMA + x32 + bias ----
    v4i a0[4];
    {
        v4i ax = *(const v4i*)(xqv);
        #pragma unroll
        for (int G = 0; G < 4; ++G) {
            v4i tx = __builtin_amdgcn_mfma_i32_16x16x64_i8(ax, Bv[G][0], zq, 0, 0, 0);
            a0[G] = tx * 32 + bias[G];
        }
    }

    // ======================= time loop (1 barrier/step) =======================
    #pragma clang loop unroll(disable)
    for (int t = 0; t < SEQn; ++t) {
        __syncthreads();                             // h(t) ready

        // h-part: 4 chunks K=64, accumulate onto 32*x + bias
        const signed char* hbR = hbRb + (t & 1) * HSLOT;
        #pragma unroll
        for (int m = 1; m <= 4; ++m) {
            v4i ah = *(const v4i*)(hbR + 64 * (m - 1));
            #pragma unroll
            for (int G = 0; G < 4; ++G)
                a0[G] = __builtin_amdgcn_mfma_i32_16x16x64_i8(ah, Bv[G][m], a0[G], 0, 0, 0);
        }

        // ---- ew: 2 items/lane (rows rowbase+rr, acc regs (q&2)+rr) ----
        signed char* wrb = wrbb + ((t + 1) & 1) * HSLOT;
        int ix_i[2], ix_f[2], ix_o[2], gj_[2];
        #pragma unroll
        for (int rr = 0; rr < 2; ++rr) {
            int gi = hi ? a0[0][2 + rr] : a0[0][rr];
            int gj = hi ? a0[1][2 + rr] : a0[1][rr];
            int gf = hi ? a0[2][2 + rr] : a0[2][rr];
            int go = hi ? a0[3][2 + rr] : a0[3][rr];
            ix_i[rr] = min(max(gi, 0), SIG_SZ - 1);  // clamp = true saturation
            ix_f[rr] = min(max(gf, 0), SIG_SZ - 1);
            ix_o[rr] = min(max(go, 0), SIG_SZ - 1);
            gj_[rr]  = gj;
        }
        int qi[2], qf[2], qo[2], qj[2];
        #pragma unroll
        for (int rr = 0; rr < 2; ++rr) {             // level-1 gathers (offset-imm)
            qi[rr] = sigt[ix_i[rr]];
            qf[rr] = sigt[ix_f[rr]];
            qo[rr] = sigt[ix_o[rr]];
            qj[rr] = tanh8[min(abs(gj_[rr]), TMAX)];
        }
        float ncv[2]; int id2[2];
        #pragma unroll
        for (int rr = 0; rr < 2; ++rr) {
            int qjs = (gj_[rr] < 0) ? -qj[rr] : qj[rr];             // odd symmetry, bit-exact
            float gc = rintf(cstf[rr] * (float)qf[rr]);             // rint(cst*qf/128), exact
            float ai = rintf((float)qi[rr] * 0.0078125f * (float)qjs); // rint(qi*qj/128), exact
            float nc = rintf(fminf(fmaxf(fmaf(ai, 0.25f, gc), -127.0f), 127.0f));
            ncv[rr] = nc;
            id2[rr] = ((int)nc + 127) + (qo[rr] << 8);              // T2 index
        }
        signed char nh[2];
        #pragma unroll
        for (int rr = 0; rr < 2; ++rr) nh[rr] = T2[id2[rr]];        // level-2 = final nh
        #pragma unroll
        for (int rr = 0; rr < 2; ++rr) {
            cstf[rr] = ncv[rr] * 0.0078125f;
            if (gok) wrb[rr * HST] = nh[rr];                        // h(t+1)
        }

        // ---- shadow for t+1: x-chunk MFMA + x32 + bias ----
        if (t != SEQn - 1) {
            v4i ax = *(const v4i*)(xqv + (t + 1) * 512);
            #pragma unroll
            for (int G = 0; G < 4; ++G) {
                v4i tx = __builtin_amdgcn_mfma_i32_16x16x64_i8(ax, Bv[G][0], zq, 0, 0, 0);
                a0[G] = tx * 32 + bias[G];
            }
        }
    }
    __syncthreads();                                 // hT = h(101) in parity 1

    // ---- finFC: out_pre = (S + 32*qfb)/4096, then qp(.., fa2=16) ----
    const signed char* hT = hbuf + 1 * HSLOT;
    if (tid < 128) {
        int b = tid >> 4, oo = (tid >> 3) & 1, ch = tid & 7;
        int S = 0;
        for (int g2 = ch * 25; g2 < ch * 25 + 25; ++g2)
            S += (int)hT[b * HST + g2] * q8f(fw[(n * 200 + g2) * 2 + oo]);
        fcred[tid] = S;
    }
    __syncthreads();
    if (tid < 16) {
        int b = tid >> 1, oo = tid & 1;
        int S = 0;
        #pragma unroll
        for (int ch = 0; ch < 8; ++ch) S += fcred[b * 16 + oo * 8 + ch];
        S += 32 * q8f(fb[n * 2 + oo]);
        float f = fminf(fmaxf((float)S * 0.001953125f, -127.f), 127.f);
        int qo2 = (int)rintf(f);
        vout[tid] = (float)qo2 * 0.125f;
    }
    __syncthreads();
    if (tid < 16) {
        int b = tid >> 1, oo = tid & 1;
        int bg = b0 + b;
        if (n < 4) { if (oo == 0) out[bg * 12 + n] = vout[b * 2] + vout[b * 2 + 1]; }
        else out[bg * 12 + 4 + 2 * (n - 4) + oo] = vout[b * 2 + oo];
    }
}

// ---------------------------------------------------------------------------
extern "C" void kernel_launch(void* const* d_in, const int* in_sizes, int n_in,
                              void* d_out, int out_size, void* d_ws, size_t ws_size,
                              hipStream_t stream) {
    (void)in_sizes; (void)n_in; (void)out_size; (void)ws_size;
    const float* x    = (const float*)d_in[0];
    const float* w_ih = (const float*)d_in[1];
    const float* w_hh = (const float*)d_in[2];
    const float* b_ih = (const float*)d_in[3];
    const float* b_hh = (const float*)d_in[4];
    const float* fw   = (const float*)d_in[15];
    const float* fb   = (const float*)d_in[16];
    unsigned long long* wsl = (unsigned long long*)d_ws;   // 2,129,920 B used

    prep_w<<<1040, 256, 0, stream>>>(w_ih, w_hh, wsl);
    lstm_k<<<256, BLK, 0, stream>>>(x, b_ih, b_hh, fw, fb, wsl, (float*)d_out);
}